// Round 9
// baseline (252.900 us; speedup 1.0000x reference)
//
#include <hip/hip_runtime.h>

// ---------------------------------------------------------------------------
// HTGT layer: sort-by-type + bf16 MFMA pipeline
// dims (fixed by problem): N=50000 M=10000 E=100000, in=128 e=32 out=128 td=32
// R=8 etypes, T=4 ntypes, H=8 heads, hs=16
// R2: k_hist/k_scatter hot-counter atomics hierarchized
// R3: register-resident-B GEMMs (fragment-major weights)
// R4 (REVERTED): prep-into-qkv fusion -> occupancy collapse
// R5: k_prep 2 edges/wave, single-pass LN, float4 gathers
// R6: 8-wave k_qkv (wash)
// R7: LDS-free k_qkv on fragment-major dia
// R8: k_prep 2 edges/32-lane-group; k_aggr LDS-caches ex[i][h]+dstlist
// R9 (REVERTED): sorted side-arrays - null on k_prep, extra setup cost
// R10 (PARTIAL REVERT): 4 edges/group caused +20MB write amplification
//     (sibling groups of a fragment block drift apart in time; partial
//     64B lines evict to HBM since dia > L2). Keep v_cvt_pk_bf16_f32.
// R11: k_prep back to 2 edges/group + pkbf. k_qkv fuses K+V GEMMs into ONE
//     pass over dia_s (shared A-fragment loads): dia_s doesn't fit L2, so
//     the former second pass re-missed to HBM; -32MB read traffic.
// ---------------------------------------------------------------------------

typedef __attribute__((ext_vector_type(8))) short short8;
typedef __attribute__((ext_vector_type(4))) float f32x4;

__device__ __forceinline__ unsigned short f2bf(float f){
  union { float f; unsigned u; } x; x.f = f;
  unsigned r = x.u + 0x7FFFu + ((x.u >> 16) & 1u);
  return (unsigned short)(r >> 16);
}
__device__ __forceinline__ float bf2f(unsigned short b){
  union { unsigned u; float f; } x; x.u = ((unsigned)b) << 16;
  return x.f;
}
// packed 2x f32 -> 2x bf16 in one u32 (lo = a, hi = b), RNE
__device__ __forceinline__ unsigned pkbf(float a, float b){
  unsigned r;
  asm("v_cvt_pk_bf16_f32 %0, %1, %2" : "=v"(r) : "v"(a), "v"(b));
  return r;
}

// ---------------- setup kernels ----------------

__global__ void k_zero(int* __restrict__ p, int n){
  int i = blockIdx.x*256 + threadIdx.x;
  if(i < n) p[i] = 0;
}

__global__ __launch_bounds__(256) void k_hist(
    const int* __restrict__ etype, const int* __restrict__ dst_idx,
    const int* __restrict__ ntype,
    int* cnt_e, int* cnt_d, int* cnt_n, int E, int M){
  __shared__ int le[8], ln[4];
  int tid = threadIdx.x;
  if(tid < 8) le[tid] = 0;
  if(tid < 4) ln[tid] = 0;
  __syncthreads();
  int g = blockIdx.x*256 + tid;
  if(g < E){ atomicAdd(&le[etype[g]], 1); atomicAdd(&cnt_d[dst_idx[g]], 1); }
  if(g < M){ atomicAdd(&ln[ntype[g]], 1); }
  __syncthreads();
  if(tid < 8 && le[tid]) atomicAdd(&cnt_e[tid], le[tid]);
  if(tid < 4 && ln[tid]) atomicAdd(&cnt_n[tid], ln[tid]);
}

// off_e is a PADDED cumsum: each etype region starts at a multiple of 64.
__global__ __launch_bounds__(1024) void k_scan(const int* __restrict__ cnt_e, int* off_e,
                                               const int* __restrict__ cnt_n, int* off_n,
                                               const int* __restrict__ cnt_d, int* off_d, int M){
  __shared__ int part[1024];
  int tid = threadIdx.x;
  if(tid == 0){
    int s = 0;
    for(int i=0;i<8;i++){ off_e[i]=s; s += ((cnt_e[i]+63)>>6)<<6; } off_e[8]=s;
    s = 0;
    for(int i=0;i<4;i++){ off_n[i]=s; s+=cnt_n[i]; } off_n[4]=s;
  }
  int per = (M + 1023) >> 10;
  int s = 0;
  for(int j=0;j<per;j++){ int idx = tid*per + j; if(idx < M) s += cnt_d[idx]; }
  part[tid] = s; __syncthreads();
  for(int o=1;o<1024;o<<=1){
    int v = (tid >= o) ? part[tid-o] : 0;
    __syncthreads();
    part[tid] += v;
    __syncthreads();
  }
  int run = (tid == 0) ? 0 : part[tid-1];
  for(int j=0;j<per;j++){
    int idx = tid*per + j;
    if(idx < M){ off_d[idx] = run; run += cnt_d[idx]; }
  }
  if(tid == 1023) off_d[M] = run;
}

__global__ __launch_bounds__(256) void k_scatter(
    const int* __restrict__ etype, const int* __restrict__ dst_idx,
    const int* __restrict__ ntype,
    const int* __restrict__ off_e, int* cur_e,
    const int* __restrict__ off_d, int* cur_d,
    const int* __restrict__ off_n, int* cur_n,
    int* eperm, int* dstlist, int* nperm, int* npos, int E, int M){
  __shared__ int lcnt[8], lbase[8], lnc[4], lnb[4];
  int tid = threadIdx.x;
  if(tid < 8) lcnt[tid] = 0;
  if(tid < 4) lnc[tid] = 0;
  __syncthreads();
  int g = blockIdx.x*256 + tid;
  int r = 0, lrank = 0, t = 0, nrank = 0;
  bool inE = (g < E), inM = (g < M);
  if(inE){ r = etype[g]; lrank = atomicAdd(&lcnt[r], 1); }
  if(inM){ t = ntype[g]; nrank = atomicAdd(&lnc[t], 1); }
  __syncthreads();
  if(tid < 8 && lcnt[tid]) lbase[tid] = atomicAdd(&cur_e[tid], lcnt[tid]);
  if(tid < 4 && lnc[tid])  lnb[tid]   = atomicAdd(&cur_n[tid], lnc[tid]);
  __syncthreads();
  if(inE){
    int p = off_e[r] + lbase[r] + lrank;
    eperm[p] = g;
    int d = dst_idx[g];
    int q = off_d[d] + atomicAdd(&cur_d[d], 1);   // ~10-way contention, benign
    dstlist[q] = p;                               // etype-sorted (padded) position
  }
  if(inM){
    int np = off_n[t] + lnb[t] + nrank;
    npos[g] = np;
    nperm[np] = g;
  }
}

// convert weights to bf16 FRAGMENT-MAJOR layout:
//   [r][nb][c][quad][m][j]  (n = nb*16+m = out col, k = c*32+quad*8+j = in dim)
// lane l (= quad*16+m) reads 16B at block_base + l*16.
__global__ void k_convw(const float* __restrict__ Wq, const float* __restrict__ Wk,
                        const float* __restrict__ Wv, const float* __restrict__ Wa,
                        unsigned short* Wq_t, unsigned short* Wk_t,
                        unsigned short* Wv_t, unsigned short* Wa_t){
  int tid = blockIdx.x*256 + threadIdx.x;
  if(tid < 131072){                                  // Wq: 8 x 128(k) x 128(n)
    int r = tid >> 14, rem = tid & 16383, k = rem >> 7, n = rem & 127;
    int nb=n>>4, m=n&15, c=k>>5, quad=(k>>3)&3, j=k&7;
    Wq_t[r*16384 + ((nb*4 + c)*4 + quad)*128 + m*8 + j] = f2bf(Wq[tid]);
  } else if(tid < 294912){                           // Wk: 8 x 160(k) x 128(n)
    int u = tid - 131072;
    int r = u / 20480, rem = u - r*20480, k = rem >> 7, n = rem & 127;
    int nb=n>>4, m=n&15, c=k>>5, quad=(k>>3)&3, j=k&7;
    Wk_t[r*20480 + ((nb*5 + c)*4 + quad)*128 + m*8 + j] = f2bf(Wk[u]);
  } else if(tid < 458752){                           // Wv: 8 x 160(k) x 128(n)
    int u = tid - 294912;
    int r = u / 20480, rem = u - r*20480, k = rem >> 7, n = rem & 127;
    int nb=n>>4, m=n&15, c=k>>5, quad=(k>>3)&3, j=k&7;
    Wv_t[r*20480 + ((nb*5 + c)*4 + quad)*128 + m*8 + j] = f2bf(Wv[u]);
  } else if(tid < 524288){                           // Wa: 4 x 128(k) x 128(n)
    int u = tid - 458752;
    int r = u >> 14, rem = u & 16383, k = rem >> 7, n = rem & 127;
    int nb=n>>4, m=n&15, c=k>>5, quad=(k>>3)&3, j=k&7;
    Wa_t[r*16384 + ((nb*4 + c)*4 + quad)*128 + m*8 + j] = f2bf(Wa[u]);
  }
}

// ---------------- prep: gather + temporal encode + LN, written FRAGMENT-MAJOR
// 2 edges per 32-lane group (R8 shape — best measured write-merge timing).
// Lane l covers elems 4l..4l+3 (float4) + edge elem l.
// dia_d: per 16-edge block, 4 chunks x [quad][m][j]; dia_s: 5 chunks.
__global__ __launch_bounds__(256) void k_prep(
  const float* __restrict__ src_h, const float* __restrict__ src_tw, const float* __restrict__ src_tb,
  const float* __restrict__ edge_h, const float* __restrict__ date,
  const int* __restrict__ src_idx, const int* __restrict__ dst_idx, const int* __restrict__ eperm,
  const float* __restrict__ g_s, const float* __restrict__ b_s,
  const float* __restrict__ g_d, const float* __restrict__ b_d,
  unsigned short* __restrict__ dia_s, unsigned short* __restrict__ dia_d, int Ep)
{
  int grp = blockIdx.x*8 + (threadIdx.x >> 5);
  int p0 = grp*2;
  if(p0 >= Ep) return;
  int l = threadIdx.x & 31;
  int pp[2]; pp[0] = p0; pp[1] = min(p0+1, Ep-1);
  int e[2];
  #pragma unroll
  for(int u=0;u<2;u++) e[u] = eperm[pp[u]];
  float t[2]; int s[2], d[2];
  #pragma unroll
  for(int u=0;u<2;u++){ t[u] = date[e[u]]; s[u] = src_idx[e[u]]; d[u] = dst_idx[e[u]]; }
  float4 sx[2], dx[2]; float xe[2];
  #pragma unroll
  for(int u=0;u<2;u++){
    sx[u] = *(const float4*)(src_h + (size_t)s[u]*128 + 4*l);   // hs
    dx[u] = *(const float4*)(src_h + (size_t)d[u]*128 + 4*l);   // hd
    xe[u] = edge_h[(size_t)e[u]*32 + l];
  }
  if(l < 8){                                 // elems 0..31 get temporal encode
    #pragma unroll
    for(int u=0;u<2;u++){
      float4 w4 = *(const float4*)(src_tw + (size_t)s[u]*32 + 4*l);
      float4 c4 = *(const float4*)(src_tb + (size_t)s[u]*32 + 4*l);
      sx[u].x = __sinf(w4.x*t[u] + c4.x) * sx[u].x;
      sx[u].y = __sinf(w4.y*t[u] + c4.y) * sx[u].y;
      sx[u].z = __sinf(w4.z*t[u] + c4.z) * sx[u].z;
      sx[u].w = __sinf(w4.w*t[u] + c4.w) * sx[u].w;
      w4 = *(const float4*)(src_tw + (size_t)d[u]*32 + 4*l);
      c4 = *(const float4*)(src_tb + (size_t)d[u]*32 + 4*l);
      dx[u].x = __sinf(w4.x*t[u] + c4.x) * dx[u].x;
      dx[u].y = __sinf(w4.y*t[u] + c4.y) * dx[u].y;
      dx[u].z = __sinf(w4.z*t[u] + c4.z) * dx[u].z;
      dx[u].w = __sinf(w4.w*t[u] + c4.w) * dx[u].w;
    }
  }
  float a1[2], a2[2], b1[2], b2[2];
  #pragma unroll
  for(int u=0;u<2;u++){
    a1[u] = sx[u].x + sx[u].y + sx[u].z + sx[u].w + xe[u];
    a2[u] = sx[u].x*sx[u].x + sx[u].y*sx[u].y + sx[u].z*sx[u].z + sx[u].w*sx[u].w + xe[u]*xe[u];
    b1[u] = dx[u].x + dx[u].y + dx[u].z + dx[u].w;
    b2[u] = dx[u].x*dx[u].x + dx[u].y*dx[u].y + dx[u].z*dx[u].z + dx[u].w*dx[u].w;
  }
  #pragma unroll
  for(int i=1;i<32;i<<=1){
    #pragma unroll
    for(int u=0;u<2;u++){
      a1[u] += __shfl_xor(a1[u],i); a2[u] += __shfl_xor(a2[u],i);
      b1[u] += __shfl_xor(b1[u],i); b2[u] += __shfl_xor(b2[u],i);
    }
  }
  float4 gs = *(const float4*)(g_s + 4*l), bs = *(const float4*)(b_s + 4*l);
  float4 gd = *(const float4*)(g_d + 4*l), bd = *(const float4*)(b_d + 4*l);
  float gs2 = g_s[128+l], bs2 = b_s[128+l];
  int cq = l >> 1;                 // (4l)>>3
  int j  = (4*l) & 7;              // 0 or 4
  #pragma unroll
  for(int u=0;u<2;u++){
    float smu = a1[u]*(1.f/160.f);
    float ssc = rsqrtf(a2[u]*(1.f/160.f) - smu*smu + 1e-5f);
    float dmu = b1[u]*(1.f/128.f);
    float dsc = rsqrtf(b2[u]*(1.f/128.f) - dmu*dmu + 1e-5f);
    uint2 rs, rd;
    rs.x = pkbf((sx[u].x-smu)*ssc*gs.x + bs.x, (sx[u].y-smu)*ssc*gs.y + bs.y);
    rs.y = pkbf((sx[u].z-smu)*ssc*gs.z + bs.z, (sx[u].w-smu)*ssc*gs.w + bs.w);
    rd.x = pkbf((dx[u].x-dmu)*dsc*gd.x + bd.x, (dx[u].y-dmu)*dsc*gd.y + bd.y);
    rd.y = pkbf((dx[u].z-dmu)*dsc*gd.z + bd.z, (dx[u].w-dmu)*dsc*gd.w + bd.w);
    int p = pp[u];
    int m = p & 15;
    size_t bs_off = (size_t)(p>>4)*2560;
    size_t bd_off = (size_t)(p>>4)*2048;
    *(uint2*)(dia_s + bs_off + cq*128 + m*8 + j) = rs;
    *(uint2*)(dia_d + bd_off + cq*128 + m*8 + j) = rd;
    dia_s[bs_off + (16 + (l>>3))*128 + m*8 + (l&7)] = f2bf((xe[u]-smu)*ssc*gs2 + bs2);
  }
}

// ---------------- LDS-free GEMM (single B): wave covers 32 rows x 32 cols
template<int NC>
__device__ __forceinline__ void gemm_nolds(
  const unsigned short* __restrict__ dia, int fb0,
  const unsigned short* __restrict__ Wf,
  int rowgrp, int colgrp, int lane, f32x4* acc)
{
  const unsigned short* a0 = dia + (size_t)(fb0 + rowgrp*2    )*NC*512 + lane*8;
  const unsigned short* a1 = dia + (size_t)(fb0 + rowgrp*2 + 1)*NC*512 + lane*8;
  const unsigned short* b0 = Wf + (size_t)(2*colgrp)*NC*512 + lane*8;
  #pragma unroll
  for(int i=0;i<4;i++) acc[i] = (f32x4){0.f,0.f,0.f,0.f};
  #pragma unroll
  for(int c=0;c<NC;c++){
    short8 bf0 = *(const short8*)(b0 + c*512);
    short8 bf1 = *(const short8*)(b0 + NC*512 + c*512);
    short8 af0 = *(const short8*)(a0 + c*512);
    short8 af1 = *(const short8*)(a1 + c*512);
    acc[0] = __builtin_amdgcn_mfma_f32_16x16x32_bf16(af0, bf0, acc[0], 0,0,0);
    acc[1] = __builtin_amdgcn_mfma_f32_16x16x32_bf16(af0, bf1, acc[1], 0,0,0);
    acc[2] = __builtin_amdgcn_mfma_f32_16x16x32_bf16(af1, bf0, acc[2], 0,0,0);
    acc[3] = __builtin_amdgcn_mfma_f32_16x16x32_bf16(af1, bf1, acc[3], 0,0,0);
  }
}

// ---------------- LDS-free DUAL GEMM: one pass over A, two B operands
// (K and V share the dia_s stream -> halves its read traffic)
template<int NC>
__device__ __forceinline__ void gemm_nolds_dual(
  const unsigned short* __restrict__ dia, int fb0,
  const unsigned short* __restrict__ WfK, const unsigned short* __restrict__ WfV,
  int rowgrp, int colgrp, int lane, f32x4* accK, f32x4* accV)
{
  const unsigned short* a0 = dia + (size_t)(fb0 + rowgrp*2    )*NC*512 + lane*8;
  const unsigned short* a1 = dia + (size_t)(fb0 + rowgrp*2 + 1)*NC*512 + lane*8;
  const unsigned short* bK = WfK + (size_t)(2*colgrp)*NC*512 + lane*8;
  const unsigned short* bV = WfV + (size_t)(2*colgrp)*NC*512 + lane*8;
  #pragma unroll
  for(int i=0;i<4;i++){
    accK[i] = (f32x4){0.f,0.f,0.f,0.f};
    accV[i] = (f32x4){0.f,0.f,0.f,0.f};
  }
  #pragma unroll
  for(int c=0;c<NC;c++){
    short8 af0 = *(const short8*)(a0 + c*512);
    short8 af1 = *(const short8*)(a1 + c*512);
    short8 bk0 = *(const short8*)(bK + c*512);
    short8 bk1 = *(const short8*)(bK + NC*512 + c*512);
    short8 bv0 = *(const short8*)(bV + c*512);
    short8 bv1 = *(const short8*)(bV + NC*512 + c*512);
    accK[0] = __builtin_amdgcn_mfma_f32_16x16x32_bf16(af0, bk0, accK[0], 0,0,0);
    accK[1] = __builtin_amdgcn_mfma_f32_16x16x32_bf16(af0, bk1, accK[1], 0,0,0);
    accK[2] = __builtin_amdgcn_mfma_f32_16x16x32_bf16(af1, bk0, accK[2], 0,0,0);
    accK[3] = __builtin_amdgcn_mfma_f32_16x16x32_bf16(af1, bk1, accK[3], 0,0,0);
    accV[0] = __builtin_amdgcn_mfma_f32_16x16x32_bf16(af0, bv0, accV[0], 0,0,0);
    accV[1] = __builtin_amdgcn_mfma_f32_16x16x32_bf16(af0, bv1, accV[1], 0,0,0);
    accV[2] = __builtin_amdgcn_mfma_f32_16x16x32_bf16(af1, bv0, accV[2], 0,0,0);
    accV[3] = __builtin_amdgcn_mfma_f32_16x16x32_bf16(af1, bv1, accV[3], 0,0,0);
  }
}

// ---------------- fused typed q/k/v GEMM + attention scores (LDS-free)
__global__ __launch_bounds__(512) void k_qkv(
  const unsigned short* __restrict__ dia_d, const unsigned short* __restrict__ dia_s,
  const unsigned short* __restrict__ Wq_t, const unsigned short* __restrict__ Wk_t,
  const unsigned short* __restrict__ Wv_t,
  const int* __restrict__ cnt_e, const int* __restrict__ off_e,
  float* __restrict__ abuf, unsigned short* __restrict__ vbuf)
{
  int bid = blockIdx.x;
  int r = -1, tl0 = 0, accT = 0;
  #pragma unroll
  for(int i=0;i<8;i++){
    int n = cnt_e[i], tt = (n + 63) >> 6;
    if(r < 0 && bid < accT + tt){ r = i; tl0 = bid - accT; }
    accT += tt;
  }
  if(r < 0) return;
  int row0 = off_e[r] + tl0*64;              // multiple of 64 (padded off_e)
  int nv = min(64, cnt_e[r] - tl0*64);
  int tid = threadIdx.x;
  int lane = tid & 63, w = tid >> 6, m = lane & 15, quad = lane >> 4;
  int rowgrp = w & 1, colgrp = w >> 1;
  int fb0 = row0 >> 4;
  f32x4 q[4], kk[4], vv[4];
  gemm_nolds<4>(dia_d, fb0, Wq_t + r*16384, rowgrp, colgrp, lane, q);
  gemm_nolds_dual<5>(dia_s, fb0, Wk_t + r*20480, Wv_t + r*20480,
                     rowgrp, colgrp, lane, kk, vv);
  const float inv = 0.08838834764831845f;
  #pragma unroll
  for(int rt=0; rt<2; rt++)
  #pragma unroll
  for(int ct=0; ct<2; ct++){
    #pragma unroll
    for(int reg=0; reg<4; reg++){
      float s = q[rt*2+ct][reg] * kk[rt*2+ct][reg];
      s += __shfl_xor(s,1); s += __shfl_xor(s,2); s += __shfl_xor(s,4); s += __shfl_xor(s,8);
      int row = rowgrp*32 + rt*16 + quad*4 + reg;
      if(m == 0 && row < nv) abuf[(size_t)(row0+row)*8 + colgrp*2 + ct] = s * inv;
    }
  }
  #pragma unroll
  for(int rt=0; rt<2; rt++)
  #pragma unroll
  for(int ct=0; ct<2; ct++)
  #pragma unroll
  for(int reg=0; reg<4; reg++){
    int row = rowgrp*32 + rt*16 + quad*4 + reg;
    if(row < nv)
      vbuf[(size_t)(row0+row)*128 + colgrp*32 + ct*16 + m] = f2bf(vv[rt*2+ct][reg]);
  }
}

// ---------------- per-dst softmax + weighted aggregate (no global atomics)
// pass 1 caches ex[i][h] + dstlist in LDS (CAP=64 >> max bucket ~30;
// correct fallback recompute for i>=CAP).
__global__ __launch_bounds__(128) void k_aggr(
  const float* __restrict__ abuf, const unsigned short* __restrict__ vbuf,
  const int* __restrict__ dstlist, const int* __restrict__ off_d,
  const int* __restrict__ npos, const int* __restrict__ ntype,
  const float* __restrict__ h_bias, unsigned short* __restrict__ hpre)
{
  const int CAP = 64;
  int d = blockIdx.x, tid = threadIdx.x;
  int o0 = off_d[d], cnt = off_d[d+1] - o0;
  __shared__ float den[8];
  __shared__ float exs[CAP*8];
  __shared__ int dl[CAP];
  if(tid < 8) den[tid] = 0.f;
  __syncthreads();
  float part = 0.f;
  int h8 = tid & 7, i0 = tid >> 3;
  for(int i = i0; i < cnt; i += 16){
    int p = dstlist[o0+i];
    float ex = __expf(abuf[(size_t)p*8 + h8]);
    part += ex;
    if(i < CAP){ exs[i*8 + h8] = ex; if(h8 == 0) dl[i] = p; }
  }
  if(part != 0.f) atomicAdd(&den[h8], part);
  __syncthreads();
  int h = tid >> 4;
  float dh = den[h];
  float rd = (dh > 0.f) ? (1.f/dh) : 0.f;
  float acc = 0.f;
  for(int i=0; i<cnt; i++){
    int p;
    float ex;
    if(i < CAP){ p = dl[i]; ex = exs[i*8 + h]; }
    else { p = dstlist[o0+i]; ex = __expf(abuf[(size_t)p*8 + h]); }
    acc += ex * rd * bf2f(vbuf[(size_t)p*128 + tid]);
  }
  int t = ntype[d];
  acc += h_bias[t*128 + tid];
  hpre[(size_t)npos[d]*128 + tid] = f2bf(acc);   // write at ntype-sorted row
}

// ---------------- GEMM core w/ LDS A (kept for k_final): 8 waves, 16c each
template<int NC>
__device__ __forceinline__ void gemm64r8(
  const unsigned short* __restrict__ A, int lda,
  const unsigned short* __restrict__ Wf,
  f32x4* acc, int tid)
{
  int lane = tid & 63, w = tid >> 6, m = lane & 15, quad = lane >> 4;
  const unsigned short* p0 = Wf + (size_t)w*NC*512 + lane*8;
  short8 b0[NC];
  #pragma unroll
  for(int c=0;c<NC;c++) b0[c] = *(const short8*)(p0 + c*512);
  #pragma unroll
  for(int i=0;i<4;i++) acc[i] = (f32x4){0.f,0.f,0.f,0.f};
  #pragma unroll
  for(int c=0;c<NC;c++){
    #pragma unroll
    for(int rt=0; rt<4; rt++){
      short8 af = *(const short8*)(A + (rt*16 + m)*lda + c*32 + quad*8);
      acc[rt] = __builtin_amdgcn_mfma_f32_16x16x32_bf16(af, b0[c], acc[rt], 0,0,0);
    }
  }
}

// ---------------- final typed GEMM (Wa) + gate + residual (8 waves)
__global__ __launch_bounds__(512) void k_final(
  const unsigned short* __restrict__ hpre, const unsigned short* __restrict__ Wa_t,
  const int* __restrict__ cnt_n, const int* __restrict__ off_n, const int* __restrict__ nperm,
  const float* __restrict__ skip, const float* __restrict__ src_h, float* __restrict__ out)
{
  __shared__ unsigned short Ah[64*136];
  int bid = blockIdx.x;
  int r = -1, tl0 = 0, accT = 0;
  #pragma unroll
  for(int i=0;i<4;i++){
    int n = cnt_n[i], tt = (n + 63) >> 6;
    if(r < 0 && bid < accT + tt){ r = i; tl0 = bid - accT; }
    accT += tt;
  }
  if(r < 0) return;
  int row0 = off_n[r] + tl0*64;
  int nv = min(64, cnt_n[r] - tl0*64);
  float gate = 1.f / (1.f + __expf(-skip[r]));
  int tid = threadIdx.x;
  int4 z = make_int4(0,0,0,0);
  #pragma unroll
  for(int it=0; it<2; it++){
    int idx = it*512 + tid, row = idx >> 4, c = idx & 15;
    int4 v = z;
    if(row < nv) v = *(const int4*)(hpre + (size_t)(row0+row)*128 + c*8);
    *(int4*)(Ah + row*136 + c*8) = v;
  }
  __syncthreads();
  f32x4 acc[4];
  gemm64r8<4>(Ah, 136, Wa_t + r*16384, acc, tid);
  int lane = tid & 63, w = tid >> 6, m = lane & 15, quad = lane >> 4;
  #pragma unroll
  for(int rt=0; rt<4; rt++)
  #pragma unroll
  for(int reg=0; reg<4; reg++){
    int row = rt*16 + quad*4 + reg;
    if(row < nv){
      int dd = nperm[row0+row];
      int col = w*16 + m;
      out[(size_t)dd*128 + col] = acc[rt][reg]*gate + src_h[(size_t)dd*128 + col]*(1.f - gate);
    }
  }
}

// ---------------------------------------------------------------------------
extern "C" void kernel_launch(void* const* d_in, const int* in_sizes, int n_in,
                              void* d_out, int out_size, void* d_ws, size_t ws_size,
                              hipStream_t stream)
{
  const float* src_h  = (const float*)d_in[0];
  const float* src_tw = (const float*)d_in[1];
  const float* src_tb = (const float*)d_in[2];
  const float* edge_h = (const float*)d_in[3];
  const float* date   = (const float*)d_in[4];
  const int*   src_idx= (const int*)d_in[5];
  const int*   dst_idx= (const int*)d_in[6];
  const int*   etype  = (const int*)d_in[7];
  const int*   ntype  = (const int*)d_in[8];
  const float* Wq     = (const float*)d_in[9];
  const float* Wk     = (const float*)d_in[10];
  const float* Wv     = (const float*)d_in[11];
  const float* Wa     = (const float*)d_in[12];
  const float* h_bias = (const float*)d_in[13];
  const float* skip   = (const float*)d_in[14];
  const float* g_s    = (const float*)d_in[15];
  const float* b_s    = (const float*)d_in[16];
  const float* g_d    = (const float*)d_in[17];
  const float* b_d    = (const float*)d_in[18];
  float* out = (float*)d_out;

  const int E = in_sizes[4];   // date
  const int M = in_sizes[8];   // ntype
  const int Ep = E + 8*63;     // upper bound on padded edge count

  char* base = (char*)d_ws;
  size_t off = 0;
  auto alloc = [&](size_t bytes)->char*{
    off = (off + 255) & ~(size_t)255;
    char* p = base + off; off += bytes; return p;
  };
  // contiguous zero region: cnt_e[8] cur_e[8] cnt_n[4] cur_n[4] cnt_d[M] cur_d[M]
  int* cnt_e = (int*)alloc((size_t)(24 + 2*M)*4);
  int* cur_e = cnt_e + 8;
  int* cnt_n = cur_e + 8;
  int* cur_n = cnt_n + 4;
  int* cnt_d = cur_n + 4;
  int* cur_d = cnt_d + M;
  const int nzero = 24 + 2*M;
  int* off_e = (int*)alloc(9*4);
  int* off_n = (int*)alloc(5*4);
  int* off_d = (int*)alloc((size_t)(M+1)*4);
  int* eperm   = (int*)alloc((size_t)Ep*4);
  int* dstlist = (int*)alloc((size_t)E*4);
  int* nperm   = (int*)alloc((size_t)M*4);
  int* npos    = (int*)alloc((size_t)M*4);
  unsigned short* Wq_t = (unsigned short*)alloc((size_t)8*128*128*2);
  unsigned short* Wk_t = (unsigned short*)alloc((size_t)8*160*128*2);
  unsigned short* Wv_t = (unsigned short*)alloc((size_t)8*160*128*2);
  unsigned short* Wa_t = (unsigned short*)alloc((size_t)4*128*128*2);
  unsigned short* dia_d = (unsigned short*)alloc((size_t)(Ep+16)*128*2);
  unsigned short* dia_s = (unsigned short*)alloc((size_t)(Ep+16)*160*2);
  unsigned short* vbuf  = (unsigned short*)alloc((size_t)Ep*128*2);
  unsigned short* hpre  = (unsigned short*)alloc((size_t)M*128*2);
  float* abuf = (float*)alloc((size_t)Ep*8*4);

  k_zero<<<dim3((nzero+255)/256), dim3(256), 0, stream>>>(cnt_e, nzero);
  k_zero<<<dim3((Ep+255)/256), dim3(256), 0, stream>>>(eperm, Ep);
  k_hist<<<dim3((E+255)/256), dim3(256), 0, stream>>>(etype, dst_idx, ntype, cnt_e, cnt_d, cnt_n, E, M);
  k_scan<<<dim3(1), dim3(1024), 0, stream>>>(cnt_e, off_e, cnt_n, off_n, cnt_d, off_d, M);
  k_scatter<<<dim3((E+255)/256), dim3(256), 0, stream>>>(etype, dst_idx, ntype,
      off_e, cur_e, off_d, cur_d, off_n, cur_n, eperm, dstlist, nperm, npos, E, M);
  k_convw<<<dim3(2048), dim3(256), 0, stream>>>(Wq, Wk, Wv, Wa, Wq_t, Wk_t, Wv_t, Wa_t);
  k_prep<<<dim3((Ep+15)/16), dim3(256), 0, stream>>>(src_h, src_tw, src_tb, edge_h, date,
      src_idx, dst_idx, eperm, g_s, b_s, g_d, b_d, dia_s, dia_d, Ep);
  k_qkv<<<dim3(E/64 + 9), dim3(512), 0, stream>>>(dia_d, dia_s, Wq_t, Wk_t, Wv_t,
      cnt_e, off_e, abuf, vbuf);
  k_aggr<<<dim3(M), dim3(128), 0, stream>>>(abuf, vbuf, dstlist, off_d, npos, ntype, h_bias, hpre);
  k_final<<<dim3(M/64 + 5), dim3(512), 0, stream>>>(hpre, Wa_t, cnt_n, off_n, nperm, skip, src_h, out);
}

// Round 10
// 249.701 us; speedup vs baseline: 1.0128x; 1.0128x over previous
//
#include <hip/hip_runtime.h>

// ---------------------------------------------------------------------------
// HTGT layer: sort-by-type + bf16 MFMA pipeline
// dims (fixed by problem): N=50000 M=10000 E=100000, in=128 e=32 out=128 td=32
// R=8 etypes, T=4 ntypes, H=8 heads, hs=16
// R2: k_hist/k_scatter hot-counter atomics hierarchized
// R3: register-resident-B GEMMs (fragment-major weights)
// R4 (REVERTED): prep-into-qkv fusion -> occupancy collapse
// R5: k_prep 2 edges/wave, single-pass LN, float4 gathers
// R6: 8-wave k_qkv (wash)
// R7: LDS-free k_qkv on fragment-major dia
// R8: k_prep 2 edges/32-lane-group; k_aggr LDS-caches ex[i][h]+dstlist
// R9 (REVERTED): sorted side-arrays - null (chain depth not the limiter)
// R10 (PARTIAL REVERT): 4 edges/group -> +20MB write amplification; kept pkbf
// R11: K+V dual GEMM (null - dia_s is L3-resident; model updated)
// R12: launch-graph cleanup: k_zero2 merges both zero launches; k_convw
//     fused into k_hist launch (independent work overlaps instead of
//     serializing); k_aggr does 2 dsts per 256-thread block (halve
//     block count + tail). k_prep accepted as gather-BW-bound (~3.3TB/s
//     effective on random 512B row-gather mix).
// ---------------------------------------------------------------------------

typedef __attribute__((ext_vector_type(8))) short short8;
typedef __attribute__((ext_vector_type(4))) float f32x4;

__device__ __forceinline__ unsigned short f2bf(float f){
  union { float f; unsigned u; } x; x.f = f;
  unsigned r = x.u + 0x7FFFu + ((x.u >> 16) & 1u);
  return (unsigned short)(r >> 16);
}
__device__ __forceinline__ float bf2f(unsigned short b){
  union { unsigned u; float f; } x; x.u = ((unsigned)b) << 16;
  return x.f;
}
// packed 2x f32 -> 2x bf16 in one u32 (lo = a, hi = b), RNE
__device__ __forceinline__ unsigned pkbf(float a, float b){
  unsigned r;
  asm("v_cvt_pk_bf16_f32 %0, %1, %2" : "=v"(r) : "v"(a), "v"(b));
  return r;
}

// ---------------- setup kernels ----------------

__global__ void k_zero2(int* __restrict__ a, int na, int* __restrict__ b, int nb){
  int i = blockIdx.x*256 + threadIdx.x;
  if(i < na) a[i] = 0;
  else if(i < na + nb) b[i - na] = 0;
}

// hist (blocks [0,HB)) + convw (blocks [HB,HB+2048)) fused: independent work
// overlaps in one launch instead of serializing across two.
__global__ __launch_bounds__(256) void k_hist_convw(
    const int* __restrict__ etype, const int* __restrict__ dst_idx,
    const int* __restrict__ ntype,
    int* cnt_e, int* cnt_d, int* cnt_n, int E, int M, int HB,
    const float* __restrict__ Wq, const float* __restrict__ Wk,
    const float* __restrict__ Wv, const float* __restrict__ Wa,
    unsigned short* Wq_t, unsigned short* Wk_t,
    unsigned short* Wv_t, unsigned short* Wa_t){
  int tid = threadIdx.x;
  if(blockIdx.x < HB){
    __shared__ int le[8], ln[4];
    if(tid < 8) le[tid] = 0;
    if(tid < 4) ln[tid] = 0;
    __syncthreads();
    int g = blockIdx.x*256 + tid;
    if(g < E){ atomicAdd(&le[etype[g]], 1); atomicAdd(&cnt_d[dst_idx[g]], 1); }
    if(g < M){ atomicAdd(&ln[ntype[g]], 1); }
    __syncthreads();
    if(tid < 8 && le[tid]) atomicAdd(&cnt_e[tid], le[tid]);
    if(tid < 4 && ln[tid]) atomicAdd(&cnt_n[tid], ln[tid]);
    return;
  }
  // convw: weights -> bf16 FRAGMENT-MAJOR [r][nb][c][quad][m][j]
  int t = (blockIdx.x - HB)*256 + tid;
  if(t < 131072){                                  // Wq: 8 x 128(k) x 128(n)
    int r = t >> 14, rem = t & 16383, k = rem >> 7, n = rem & 127;
    int nb=n>>4, m=n&15, c=k>>5, quad=(k>>3)&3, j=k&7;
    Wq_t[r*16384 + ((nb*4 + c)*4 + quad)*128 + m*8 + j] = f2bf(Wq[t]);
  } else if(t < 294912){                           // Wk: 8 x 160(k) x 128(n)
    int u = t - 131072;
    int r = u / 20480, rem = u - r*20480, k = rem >> 7, n = rem & 127;
    int nb=n>>4, m=n&15, c=k>>5, quad=(k>>3)&3, j=k&7;
    Wk_t[r*20480 + ((nb*5 + c)*4 + quad)*128 + m*8 + j] = f2bf(Wk[u]);
  } else if(t < 458752){                           // Wv: 8 x 160(k) x 128(n)
    int u = t - 294912;
    int r = u / 20480, rem = u - r*20480, k = rem >> 7, n = rem & 127;
    int nb=n>>4, m=n&15, c=k>>5, quad=(k>>3)&3, j=k&7;
    Wv_t[r*20480 + ((nb*5 + c)*4 + quad)*128 + m*8 + j] = f2bf(Wv[u]);
  } else if(t < 524288){                           // Wa: 4 x 128(k) x 128(n)
    int u = t - 458752;
    int r = u >> 14, rem = u & 16383, k = rem >> 7, n = rem & 127;
    int nb=n>>4, m=n&15, c=k>>5, quad=(k>>3)&3, j=k&7;
    Wa_t[r*16384 + ((nb*4 + c)*4 + quad)*128 + m*8 + j] = f2bf(Wa[u]);
  }
}

// off_e is a PADDED cumsum: each etype region starts at a multiple of 64.
__global__ __launch_bounds__(1024) void k_scan(const int* __restrict__ cnt_e, int* off_e,
                                               const int* __restrict__ cnt_n, int* off_n,
                                               const int* __restrict__ cnt_d, int* off_d, int M){
  __shared__ int part[1024];
  int tid = threadIdx.x;
  if(tid == 0){
    int s = 0;
    for(int i=0;i<8;i++){ off_e[i]=s; s += ((cnt_e[i]+63)>>6)<<6; } off_e[8]=s;
    s = 0;
    for(int i=0;i<4;i++){ off_n[i]=s; s+=cnt_n[i]; } off_n[4]=s;
  }
  int per = (M + 1023) >> 10;
  int s = 0;
  for(int j=0;j<per;j++){ int idx = tid*per + j; if(idx < M) s += cnt_d[idx]; }
  part[tid] = s; __syncthreads();
  for(int o=1;o<1024;o<<=1){
    int v = (tid >= o) ? part[tid-o] : 0;
    __syncthreads();
    part[tid] += v;
    __syncthreads();
  }
  int run = (tid == 0) ? 0 : part[tid-1];
  for(int j=0;j<per;j++){
    int idx = tid*per + j;
    if(idx < M){ off_d[idx] = run; run += cnt_d[idx]; }
  }
  if(tid == 1023) off_d[M] = run;
}

__global__ __launch_bounds__(256) void k_scatter(
    const int* __restrict__ etype, const int* __restrict__ dst_idx,
    const int* __restrict__ ntype,
    const int* __restrict__ off_e, int* cur_e,
    const int* __restrict__ off_d, int* cur_d,
    const int* __restrict__ off_n, int* cur_n,
    int* eperm, int* dstlist, int* nperm, int* npos, int E, int M){
  __shared__ int lcnt[8], lbase[8], lnc[4], lnb[4];
  int tid = threadIdx.x;
  if(tid < 8) lcnt[tid] = 0;
  if(tid < 4) lnc[tid] = 0;
  __syncthreads();
  int g = blockIdx.x*256 + tid;
  int r = 0, lrank = 0, t = 0, nrank = 0;
  bool inE = (g < E), inM = (g < M);
  if(inE){ r = etype[g]; lrank = atomicAdd(&lcnt[r], 1); }
  if(inM){ t = ntype[g]; nrank = atomicAdd(&lnc[t], 1); }
  __syncthreads();
  if(tid < 8 && lcnt[tid]) lbase[tid] = atomicAdd(&cur_e[tid], lcnt[tid]);
  if(tid < 4 && lnc[tid])  lnb[tid]   = atomicAdd(&cur_n[tid], lnc[tid]);
  __syncthreads();
  if(inE){
    int p = off_e[r] + lbase[r] + lrank;
    eperm[p] = g;
    int d = dst_idx[g];
    int q = off_d[d] + atomicAdd(&cur_d[d], 1);   // ~10-way contention, benign
    dstlist[q] = p;                               // etype-sorted (padded) position
  }
  if(inM){
    int np = off_n[t] + lnb[t] + nrank;
    npos[g] = np;
    nperm[np] = g;
  }
}

// ---------------- prep: gather + temporal encode + LN, written FRAGMENT-MAJOR
// 2 edges per 32-lane group (best measured write-merge timing).
// Lane l covers elems 4l..4l+3 (float4) + edge elem l.
// dia_d: per 16-edge block, 4 chunks x [quad][m][j]; dia_s: 5 chunks.
__global__ __launch_bounds__(256) void k_prep(
  const float* __restrict__ src_h, const float* __restrict__ src_tw, const float* __restrict__ src_tb,
  const float* __restrict__ edge_h, const float* __restrict__ date,
  const int* __restrict__ src_idx, const int* __restrict__ dst_idx, const int* __restrict__ eperm,
  const float* __restrict__ g_s, const float* __restrict__ b_s,
  const float* __restrict__ g_d, const float* __restrict__ b_d,
  unsigned short* __restrict__ dia_s, unsigned short* __restrict__ dia_d, int Ep)
{
  int grp = blockIdx.x*8 + (threadIdx.x >> 5);
  int p0 = grp*2;
  if(p0 >= Ep) return;
  int l = threadIdx.x & 31;
  int pp[2]; pp[0] = p0; pp[1] = min(p0+1, Ep-1);
  int e[2];
  #pragma unroll
  for(int u=0;u<2;u++) e[u] = eperm[pp[u]];
  float t[2]; int s[2], d[2];
  #pragma unroll
  for(int u=0;u<2;u++){ t[u] = date[e[u]]; s[u] = src_idx[e[u]]; d[u] = dst_idx[e[u]]; }
  float4 sx[2], dx[2]; float xe[2];
  #pragma unroll
  for(int u=0;u<2;u++){
    sx[u] = *(const float4*)(src_h + (size_t)s[u]*128 + 4*l);   // hs
    dx[u] = *(const float4*)(src_h + (size_t)d[u]*128 + 4*l);   // hd
    xe[u] = edge_h[(size_t)e[u]*32 + l];
  }
  if(l < 8){                                 // elems 0..31 get temporal encode
    #pragma unroll
    for(int u=0;u<2;u++){
      float4 w4 = *(const float4*)(src_tw + (size_t)s[u]*32 + 4*l);
      float4 c4 = *(const float4*)(src_tb + (size_t)s[u]*32 + 4*l);
      sx[u].x = __sinf(w4.x*t[u] + c4.x) * sx[u].x;
      sx[u].y = __sinf(w4.y*t[u] + c4.y) * sx[u].y;
      sx[u].z = __sinf(w4.z*t[u] + c4.z) * sx[u].z;
      sx[u].w = __sinf(w4.w*t[u] + c4.w) * sx[u].w;
      w4 = *(const float4*)(src_tw + (size_t)d[u]*32 + 4*l);
      c4 = *(const float4*)(src_tb + (size_t)d[u]*32 + 4*l);
      dx[u].x = __sinf(w4.x*t[u] + c4.x) * dx[u].x;
      dx[u].y = __sinf(w4.y*t[u] + c4.y) * dx[u].y;
      dx[u].z = __sinf(w4.z*t[u] + c4.z) * dx[u].z;
      dx[u].w = __sinf(w4.w*t[u] + c4.w) * dx[u].w;
    }
  }
  float a1[2], a2[2], b1[2], b2[2];
  #pragma unroll
  for(int u=0;u<2;u++){
    a1[u] = sx[u].x + sx[u].y + sx[u].z + sx[u].w + xe[u];
    a2[u] = sx[u].x*sx[u].x + sx[u].y*sx[u].y + sx[u].z*sx[u].z + sx[u].w*sx[u].w + xe[u]*xe[u];
    b1[u] = dx[u].x + dx[u].y + dx[u].z + dx[u].w;
    b2[u] = dx[u].x*dx[u].x + dx[u].y*dx[u].y + dx[u].z*dx[u].z + dx[u].w*dx[u].w;
  }
  #pragma unroll
  for(int i=1;i<32;i<<=1){
    #pragma unroll
    for(int u=0;u<2;u++){
      a1[u] += __shfl_xor(a1[u],i); a2[u] += __shfl_xor(a2[u],i);
      b1[u] += __shfl_xor(b1[u],i); b2[u] += __shfl_xor(b2[u],i);
    }
  }
  float4 gs = *(const float4*)(g_s + 4*l), bs = *(const float4*)(b_s + 4*l);
  float4 gd = *(const float4*)(g_d + 4*l), bd = *(const float4*)(b_d + 4*l);
  float gs2 = g_s[128+l], bs2 = b_s[128+l];
  int cq = l >> 1;                 // (4l)>>3
  int j  = (4*l) & 7;              // 0 or 4
  #pragma unroll
  for(int u=0;u<2;u++){
    float smu = a1[u]*(1.f/160.f);
    float ssc = rsqrtf(a2[u]*(1.f/160.f) - smu*smu + 1e-5f);
    float dmu = b1[u]*(1.f/128.f);
    float dsc = rsqrtf(b2[u]*(1.f/128.f) - dmu*dmu + 1e-5f);
    uint2 rs, rd;
    rs.x = pkbf((sx[u].x-smu)*ssc*gs.x + bs.x, (sx[u].y-smu)*ssc*gs.y + bs.y);
    rs.y = pkbf((sx[u].z-smu)*ssc*gs.z + bs.z, (sx[u].w-smu)*ssc*gs.w + bs.w);
    rd.x = pkbf((dx[u].x-dmu)*dsc*gd.x + bd.x, (dx[u].y-dmu)*dsc*gd.y + bd.y);
    rd.y = pkbf((dx[u].z-dmu)*dsc*gd.z + bd.z, (dx[u].w-dmu)*dsc*gd.w + bd.w);
    int p = pp[u];
    int m = p & 15;
    size_t bs_off = (size_t)(p>>4)*2560;
    size_t bd_off = (size_t)(p>>4)*2048;
    *(uint2*)(dia_s + bs_off + cq*128 + m*8 + j) = rs;
    *(uint2*)(dia_d + bd_off + cq*128 + m*8 + j) = rd;
    dia_s[bs_off + (16 + (l>>3))*128 + m*8 + (l&7)] = f2bf((xe[u]-smu)*ssc*gs2 + bs2);
  }
}

// ---------------- LDS-free GEMM (single B): wave covers 32 rows x 32 cols
template<int NC>
__device__ __forceinline__ void gemm_nolds(
  const unsigned short* __restrict__ dia, int fb0,
  const unsigned short* __restrict__ Wf,
  int rowgrp, int colgrp, int lane, f32x4* acc)
{
  const unsigned short* a0 = dia + (size_t)(fb0 + rowgrp*2    )*NC*512 + lane*8;
  const unsigned short* a1 = dia + (size_t)(fb0 + rowgrp*2 + 1)*NC*512 + lane*8;
  const unsigned short* b0 = Wf + (size_t)(2*colgrp)*NC*512 + lane*8;
  #pragma unroll
  for(int i=0;i<4;i++) acc[i] = (f32x4){0.f,0.f,0.f,0.f};
  #pragma unroll
  for(int c=0;c<NC;c++){
    short8 bf0 = *(const short8*)(b0 + c*512);
    short8 bf1 = *(const short8*)(b0 + NC*512 + c*512);
    short8 af0 = *(const short8*)(a0 + c*512);
    short8 af1 = *(const short8*)(a1 + c*512);
    acc[0] = __builtin_amdgcn_mfma_f32_16x16x32_bf16(af0, bf0, acc[0], 0,0,0);
    acc[1] = __builtin_amdgcn_mfma_f32_16x16x32_bf16(af0, bf1, acc[1], 0,0,0);
    acc[2] = __builtin_amdgcn_mfma_f32_16x16x32_bf16(af1, bf0, acc[2], 0,0,0);
    acc[3] = __builtin_amdgcn_mfma_f32_16x16x32_bf16(af1, bf1, acc[3], 0,0,0);
  }
}

// ---------------- LDS-free DUAL GEMM: one pass over A, two B operands
template<int NC>
__device__ __forceinline__ void gemm_nolds_dual(
  const unsigned short* __restrict__ dia, int fb0,
  const unsigned short* __restrict__ WfK, const unsigned short* __restrict__ WfV,
  int rowgrp, int colgrp, int lane, f32x4* accK, f32x4* accV)
{
  const unsigned short* a0 = dia + (size_t)(fb0 + rowgrp*2    )*NC*512 + lane*8;
  const unsigned short* a1 = dia + (size_t)(fb0 + rowgrp*2 + 1)*NC*512 + lane*8;
  const unsigned short* bK = WfK + (size_t)(2*colgrp)*NC*512 + lane*8;
  const unsigned short* bV = WfV + (size_t)(2*colgrp)*NC*512 + lane*8;
  #pragma unroll
  for(int i=0;i<4;i++){
    accK[i] = (f32x4){0.f,0.f,0.f,0.f};
    accV[i] = (f32x4){0.f,0.f,0.f,0.f};
  }
  #pragma unroll
  for(int c=0;c<NC;c++){
    short8 af0 = *(const short8*)(a0 + c*512);
    short8 af1 = *(const short8*)(a1 + c*512);
    short8 bk0 = *(const short8*)(bK + c*512);
    short8 bk1 = *(const short8*)(bK + NC*512 + c*512);
    short8 bv0 = *(const short8*)(bV + c*512);
    short8 bv1 = *(const short8*)(bV + NC*512 + c*512);
    accK[0] = __builtin_amdgcn_mfma_f32_16x16x32_bf16(af0, bk0, accK[0], 0,0,0);
    accK[1] = __builtin_amdgcn_mfma_f32_16x16x32_bf16(af0, bk1, accK[1], 0,0,0);
    accK[2] = __builtin_amdgcn_mfma_f32_16x16x32_bf16(af1, bk0, accK[2], 0,0,0);
    accK[3] = __builtin_amdgcn_mfma_f32_16x16x32_bf16(af1, bk1, accK[3], 0,0,0);
    accV[0] = __builtin_amdgcn_mfma_f32_16x16x32_bf16(af0, bv0, accV[0], 0,0,0);
    accV[1] = __builtin_amdgcn_mfma_f32_16x16x32_bf16(af0, bv1, accV[1], 0,0,0);
    accV[2] = __builtin_amdgcn_mfma_f32_16x16x32_bf16(af1, bv0, accV[2], 0,0,0);
    accV[3] = __builtin_amdgcn_mfma_f32_16x16x32_bf16(af1, bv1, accV[3], 0,0,0);
  }
}

// ---------------- fused typed q/k/v GEMM + attention scores (LDS-free)
__global__ __launch_bounds__(512) void k_qkv(
  const unsigned short* __restrict__ dia_d, const unsigned short* __restrict__ dia_s,
  const unsigned short* __restrict__ Wq_t, const unsigned short* __restrict__ Wk_t,
  const unsigned short* __restrict__ Wv_t,
  const int* __restrict__ cnt_e, const int* __restrict__ off_e,
  float* __restrict__ abuf, unsigned short* __restrict__ vbuf)
{
  int bid = blockIdx.x;
  int r = -1, tl0 = 0, accT = 0;
  #pragma unroll
  for(int i=0;i<8;i++){
    int n = cnt_e[i], tt = (n + 63) >> 6;
    if(r < 0 && bid < accT + tt){ r = i; tl0 = bid - accT; }
    accT += tt;
  }
  if(r < 0) return;
  int row0 = off_e[r] + tl0*64;              // multiple of 64 (padded off_e)
  int nv = min(64, cnt_e[r] - tl0*64);
  int tid = threadIdx.x;
  int lane = tid & 63, w = tid >> 6, m = lane & 15, quad = lane >> 4;
  int rowgrp = w & 1, colgrp = w >> 1;
  int fb0 = row0 >> 4;
  f32x4 q[4], kk[4], vv[4];
  gemm_nolds<4>(dia_d, fb0, Wq_t + r*16384, rowgrp, colgrp, lane, q);
  gemm_nolds_dual<5>(dia_s, fb0, Wk_t + r*20480, Wv_t + r*20480,
                     rowgrp, colgrp, lane, kk, vv);
  const float inv = 0.08838834764831845f;
  #pragma unroll
  for(int rt=0; rt<2; rt++)
  #pragma unroll
  for(int ct=0; ct<2; ct++){
    #pragma unroll
    for(int reg=0; reg<4; reg++){
      float s = q[rt*2+ct][reg] * kk[rt*2+ct][reg];
      s += __shfl_xor(s,1); s += __shfl_xor(s,2); s += __shfl_xor(s,4); s += __shfl_xor(s,8);
      int row = rowgrp*32 + rt*16 + quad*4 + reg;
      if(m == 0 && row < nv) abuf[(size_t)(row0+row)*8 + colgrp*2 + ct] = s * inv;
    }
  }
  #pragma unroll
  for(int rt=0; rt<2; rt++)
  #pragma unroll
  for(int ct=0; ct<2; ct++)
  #pragma unroll
  for(int reg=0; reg<4; reg++){
    int row = rowgrp*32 + rt*16 + quad*4 + reg;
    if(row < nv)
      vbuf[(size_t)(row0+row)*128 + colgrp*32 + ct*16 + m] = f2bf(vv[rt*2+ct][reg]);
  }
}

// ---------------- per-dst softmax + weighted aggregate (no global atomics)
// 2 dsts per 256-thread block; per-dst half caches ex[i][h] + dstlist in LDS
// (CAP=64 >> max bucket ~30; correct fallback recompute for i>=CAP).
__global__ __launch_bounds__(256) void k_aggr(
  const float* __restrict__ abuf, const unsigned short* __restrict__ vbuf,
  const int* __restrict__ dstlist, const int* __restrict__ off_d,
  const int* __restrict__ npos, const int* __restrict__ ntype,
  const float* __restrict__ h_bias, unsigned short* __restrict__ hpre, int M)
{
  const int CAP = 64;
  int sub = threadIdx.x >> 7;                 // 0 or 1
  int tid = threadIdx.x & 127;
  int d = blockIdx.x*2 + sub;
  bool act = (d < M);
  __shared__ float den[2][8];
  __shared__ float exs[2][CAP*8];
  __shared__ int dl[2][CAP];
  if(tid < 8) den[sub][tid] = 0.f;
  __syncthreads();
  int o0 = 0, cnt = 0;
  if(act){ o0 = off_d[d]; cnt = off_d[d+1] - o0; }
  float part = 0.f;
  int h8 = tid & 7, i0 = tid >> 3;
  for(int i = i0; i < cnt; i += 16){
    int p = dstlist[o0+i];
    float ex = __expf(abuf[(size_t)p*8 + h8]);
    part += ex;
    if(i < CAP){ exs[sub][i*8 + h8] = ex; if(h8 == 0) dl[sub][i] = p; }
  }
  if(part != 0.f) atomicAdd(&den[sub][h8], part);
  __syncthreads();
  if(!act) return;
  int h = tid >> 4;
  float dh = den[sub][h];
  float rd = (dh > 0.f) ? (1.f/dh) : 0.f;
  float acc = 0.f;
  for(int i=0; i<cnt; i++){
    int p;
    float ex;
    if(i < CAP){ p = dl[sub][i]; ex = exs[sub][i*8 + h]; }
    else { p = dstlist[o0+i]; ex = __expf(abuf[(size_t)p*8 + h]); }
    acc += ex * rd * bf2f(vbuf[(size_t)p*128 + tid]);
  }
  int t = ntype[d];
  acc += h_bias[t*128 + tid];
  hpre[(size_t)npos[d]*128 + tid] = f2bf(acc);   // write at ntype-sorted row
}

// ---------------- GEMM core w/ LDS A (kept for k_final): 8 waves, 16c each
template<int NC>
__device__ __forceinline__ void gemm64r8(
  const unsigned short* __restrict__ A, int lda,
  const unsigned short* __restrict__ Wf,
  f32x4* acc, int tid)
{
  int lane = tid & 63, w = tid >> 6, m = lane & 15, quad = lane >> 4;
  const unsigned short* p0 = Wf + (size_t)w*NC*512 + lane*8;
  short8 b0[NC];
  #pragma unroll
  for(int c=0;c<NC;c++) b0[c] = *(const short8*)(p0 + c*512);
  #pragma unroll
  for(int i=0;i<4;i++) acc[i] = (f32x4){0.f,0.f,0.f,0.f};
  #pragma unroll
  for(int c=0;c<NC;c++){
    #pragma unroll
    for(int rt=0; rt<4; rt++){
      short8 af = *(const short8*)(A + (rt*16 + m)*lda + c*32 + quad*8);
      acc[rt] = __builtin_amdgcn_mfma_f32_16x16x32_bf16(af, b0[c], acc[rt], 0,0,0);
    }
  }
}

// ---------------- final typed GEMM (Wa) + gate + residual (8 waves)
__global__ __launch_bounds__(512) void k_final(
  const unsigned short* __restrict__ hpre, const unsigned short* __restrict__ Wa_t,
  const int* __restrict__ cnt_n, const int* __restrict__ off_n, const int* __restrict__ nperm,
  const float* __restrict__ skip, const float* __restrict__ src_h, float* __restrict__ out)
{
  __shared__ unsigned short Ah[64*136];
  int bid = blockIdx.x;
  int r = -1, tl0 = 0, accT = 0;
  #pragma unroll
  for(int i=0;i<4;i++){
    int n = cnt_n[i], tt = (n + 63) >> 6;
    if(r < 0 && bid < accT + tt){ r = i; tl0 = bid - accT; }
    accT += tt;
  }
  if(r < 0) return;
  int row0 = off_n[r] + tl0*64;
  int nv = min(64, cnt_n[r] - tl0*64);
  float gate = 1.f / (1.f + __expf(-skip[r]));
  int tid = threadIdx.x;
  int4 z = make_int4(0,0,0,0);
  #pragma unroll
  for(int it=0; it<2; it++){
    int idx = it*512 + tid, row = idx >> 4, c = idx & 15;
    int4 v = z;
    if(row < nv) v = *(const int4*)(hpre + (size_t)(row0+row)*128 + c*8);
    *(int4*)(Ah + row*136 + c*8) = v;
  }
  __syncthreads();
  f32x4 acc[4];
  gemm64r8<4>(Ah, 136, Wa_t + r*16384, acc, tid);
  int lane = tid & 63, w = tid >> 6, m = lane & 15, quad = lane >> 4;
  #pragma unroll
  for(int rt=0; rt<4; rt++)
  #pragma unroll
  for(int reg=0; reg<4; reg++){
    int row = rt*16 + quad*4 + reg;
    if(row < nv){
      int dd = nperm[row0+row];
      int col = w*16 + m;
      out[(size_t)dd*128 + col] = acc[rt][reg]*gate + src_h[(size_t)dd*128 + col]*(1.f - gate);
    }
  }
}

// ---------------------------------------------------------------------------
extern "C" void kernel_launch(void* const* d_in, const int* in_sizes, int n_in,
                              void* d_out, int out_size, void* d_ws, size_t ws_size,
                              hipStream_t stream)
{
  const float* src_h  = (const float*)d_in[0];
  const float* src_tw = (const float*)d_in[1];
  const float* src_tb = (const float*)d_in[2];
  const float* edge_h = (const float*)d_in[3];
  const float* date   = (const float*)d_in[4];
  const int*   src_idx= (const int*)d_in[5];
  const int*   dst_idx= (const int*)d_in[6];
  const int*   etype  = (const int*)d_in[7];
  const int*   ntype  = (const int*)d_in[8];
  const float* Wq     = (const float*)d_in[9];
  const float* Wk     = (const float*)d_in[10];
  const float* Wv     = (const float*)d_in[11];
  const float* Wa     = (const float*)d_in[12];
  const float* h_bias = (const float*)d_in[13];
  const float* skip   = (const float*)d_in[14];
  const float* g_s    = (const float*)d_in[15];
  const float* b_s    = (const float*)d_in[16];
  const float* g_d    = (const float*)d_in[17];
  const float* b_d    = (const float*)d_in[18];
  float* out = (float*)d_out;

  const int E = in_sizes[4];   // date
  const int M = in_sizes[8];   // ntype
  const int Ep = E + 8*63;     // upper bound on padded edge count

  char* base = (char*)d_ws;
  size_t off = 0;
  auto alloc = [&](size_t bytes)->char*{
    off = (off + 255) & ~(size_t)255;
    char* p = base + off; off += bytes; return p;
  };
  // contiguous zero region: cnt_e[8] cur_e[8] cnt_n[4] cur_n[4] cnt_d[M] cur_d[M]
  int* cnt_e = (int*)alloc((size_t)(24 + 2*M)*4);
  int* cur_e = cnt_e + 8;
  int* cnt_n = cur_e + 8;
  int* cur_n = cnt_n + 4;
  int* cnt_d = cur_n + 4;
  int* cur_d = cnt_d + M;
  const int nzero = 24 + 2*M;
  int* off_e = (int*)alloc(9*4);
  int* off_n = (int*)alloc(5*4);
  int* off_d = (int*)alloc((size_t)(M+1)*4);
  int* eperm   = (int*)alloc((size_t)Ep*4);
  int* dstlist = (int*)alloc((size_t)E*4);
  int* nperm   = (int*)alloc((size_t)M*4);
  int* npos    = (int*)alloc((size_t)M*4);
  unsigned short* Wq_t = (unsigned short*)alloc((size_t)8*128*128*2);
  unsigned short* Wk_t = (unsigned short*)alloc((size_t)8*160*128*2);
  unsigned short* Wv_t = (unsigned short*)alloc((size_t)8*160*128*2);
  unsigned short* Wa_t = (unsigned short*)alloc((size_t)4*128*128*2);
  unsigned short* dia_d = (unsigned short*)alloc((size_t)(Ep+16)*128*2);
  unsigned short* dia_s = (unsigned short*)alloc((size_t)(Ep+16)*160*2);
  unsigned short* vbuf  = (unsigned short*)alloc((size_t)Ep*128*2);
  unsigned short* hpre  = (unsigned short*)alloc((size_t)M*128*2);
  float* abuf = (float*)alloc((size_t)Ep*8*4);

  const int HB = (E + 255)/256;
  k_zero2<<<dim3((nzero + Ep + 255)/256), dim3(256), 0, stream>>>(cnt_e, nzero, eperm, Ep);
  k_hist_convw<<<dim3(HB + 2048), dim3(256), 0, stream>>>(etype, dst_idx, ntype,
      cnt_e, cnt_d, cnt_n, E, M, HB,
      Wq, Wk, Wv, Wa, Wq_t, Wk_t, Wv_t, Wa_t);
  k_scan<<<dim3(1), dim3(1024), 0, stream>>>(cnt_e, off_e, cnt_n, off_n, cnt_d, off_d, M);
  k_scatter<<<dim3(HB), dim3(256), 0, stream>>>(etype, dst_idx, ntype,
      off_e, cur_e, off_d, cur_d, off_n, cur_n, eperm, dstlist, nperm, npos, E, M);
  k_prep<<<dim3((Ep+15)/16), dim3(256), 0, stream>>>(src_h, src_tw, src_tb, edge_h, date,
      src_idx, dst_idx, eperm, g_s, b_s, g_d, b_d, dia_s, dia_d, Ep);
  k_qkv<<<dim3(E/64 + 9), dim3(512), 0, stream>>>(dia_d, dia_s, Wq_t, Wk_t, Wv_t,
      cnt_e, off_e, abuf, vbuf);
  k_aggr<<<dim3((M+1)/2), dim3(256), 0, stream>>>(abuf, vbuf, dstlist, off_d, npos, ntype, h_bias, hpre, M);
  k_final<<<dim3(M/64 + 5), dim3(512), 0, stream>>>(hpre, Wa_t, cnt_n, off_n, nperm, skip, src_h, out);
}